// Round 2
// baseline (3284.219 us; speedup 1.0000x reference)
//
#include <hip/hip_runtime.h>
#include <hip/hip_bf16.h>

#define D_MODEL 256
#define D_INNER 512
#define D_STATE 16
#define D_CONV 4
#define DT_RANK 16
#define N_LAYERS 4
#define CITY 300
#define BATCH 32
#define SEQ 300
#define NTOK (BATCH * SEQ)   // 9600

// ---------------- embedding: x[t,d] = c0*W[d,0] + c1*W[d,1] + b[d] ----------------
__global__ void embed_kernel(const float* __restrict__ coords,
                             const float* __restrict__ eW,
                             const float* __restrict__ eb,
                             float* __restrict__ x) {
    int t = blockIdx.x, d = threadIdx.x;
    float c0 = coords[t * 2 + 0];
    float c1 = coords[t * 2 + 1];
    x[t * D_MODEL + d] = c0 * eW[d * 2 + 0] + c1 * eW[d * 2 + 1] + eb[d];
}

// ------------- residual add + layernorm: resid = x (+resid); h = LN(resid) -------------
__global__ void ln_res_kernel(const float* __restrict__ xin, float* __restrict__ resid,
                              float* __restrict__ h,
                              const float* __restrict__ w,
                              const float* __restrict__ b, int first) {
    int t = blockIdx.x, d = threadIdx.x;
    float r = xin[t * D_MODEL + d] + (first ? 0.f : resid[t * D_MODEL + d]);
    resid[t * D_MODEL + d] = r;
    __shared__ float s1[D_MODEL], s2[D_MODEL];
    s1[d] = r; s2[d] = r * r;
    __syncthreads();
    for (int off = D_MODEL / 2; off > 0; off >>= 1) {
        if (d < off) { s1[d] += s1[d + off]; s2[d] += s2[d + off]; }
        __syncthreads();
    }
    float mean = s1[0] * (1.f / D_MODEL);
    float var = s2[0] * (1.f / D_MODEL) - mean * mean;
    h[t * D_MODEL + d] = (r - mean) * rsqrtf(var + 1e-5f) * w[d] + b[d];
}

// ------------- final add + RMSNorm -------------
__global__ void final_rms_kernel(const float* __restrict__ xin, const float* __restrict__ resid,
                                 const float* __restrict__ w,
                                 const float* __restrict__ b, float* __restrict__ h) {
    int t = blockIdx.x, d = threadIdx.x;
    float r = xin[t * D_MODEL + d] + resid[t * D_MODEL + d];
    __shared__ float s2[D_MODEL];
    s2[d] = r * r;
    __syncthreads();
    for (int off = D_MODEL / 2; off > 0; off >>= 1) {
        if (d < off) s2[d] += s2[d + off];
        __syncthreads();
    }
    float rms = r * rsqrtf(s2[0] * (1.f / D_MODEL) + 1e-5f);
    h[t * D_MODEL + d] = rms * w[d] + b[d];
}

// ------------- generic token GEMM: C[t,n] = sum_k A[t,k] * W[n,k] -------------
// block: 256 threads, TT tokens per block staged in LDS; grid (T/TT, ceil(N/256))
template <int TT>
__global__ void gemm_tk(const float* __restrict__ A, const float* __restrict__ W,
                        float* __restrict__ C, int N, int K) {
    extern __shared__ float lds[];  // TT*K floats
    int t0 = blockIdx.x * TT;
    int n = blockIdx.y * blockDim.x + threadIdx.x;
    for (int idx = threadIdx.x; idx < TT * K; idx += blockDim.x)
        lds[idx] = A[(size_t)(t0 + idx / K) * K + (idx % K)];
    __syncthreads();
    if (n < N) {
        float acc[TT];
#pragma unroll
        for (int tt = 0; tt < TT; tt++) acc[tt] = 0.f;
        const float4* Wr = (const float4*)(W + (size_t)n * K);
        for (int k4 = 0; k4 < K / 4; k4++) {
            float4 w = Wr[k4];
            int k = k4 * 4;
#pragma unroll
            for (int tt = 0; tt < TT; tt++)
                acc[tt] += lds[tt * K + k] * w.x + lds[tt * K + k + 1] * w.y +
                           lds[tt * K + k + 2] * w.z + lds[tt * K + k + 3] * w.w;
        }
#pragma unroll
        for (int tt = 0; tt < TT; tt++)
            C[(size_t)(t0 + tt) * N + n] = acc[tt];
    }
}

// ------------- causal depthwise conv (k=4) + bias + SiLU; xi = xz[..., 0:512] -------------
__global__ void conv_silu_kernel(const float* __restrict__ xz,
                                 const float* __restrict__ cW,
                                 const float* __restrict__ cb,
                                 float* __restrict__ xc) {
    int idx = blockIdx.x * blockDim.x + threadIdx.x;  // t*512 + d
    int d = idx & (D_INNER - 1);
    int t = idx >> 9;
    int l = t % SEQ;
    int base = t - l;  // b*SEQ
    float acc = cb[d];
#pragma unroll
    for (int k = 0; k < D_CONV; k++) {
        int ll = l - (D_CONV - 1) + k;
        if (ll >= 0)
            acc += xz[(size_t)(base + ll) * (2 * D_INNER) + d] * cW[d * D_CONV + k];
    }
    xc[idx] = acc / (1.f + __expf(-acc));  // acc * sigmoid(acc)
}

// ------------- xproj: dbl[t,j] = sum_d xc[t,d] * xW[j,d], j in [0,48) -------------
__global__ void xproj_kernel(const float* __restrict__ xc, const float* __restrict__ xW,
                             float* __restrict__ dbl) {
    int t = blockIdx.x, j = threadIdx.x;
    if (j < DT_RANK + 2 * D_STATE) {
        const float* Wr = xW + j * D_INNER;
        const float* xr = xc + (size_t)t * D_INNER;
        float acc = 0.f;
        for (int dd = 0; dd < D_INNER; dd++) acc += xr[dd] * Wr[dd];
        dbl[t * 48 + j] = acc;
    }
}

// ------------- dtproj + softplus: dt[t,d] = softplus(sum_r dbl[t,r]*dW[d,r] + db[d]) -------------
__global__ void dtproj_kernel(const float* __restrict__ dbl, const float* __restrict__ dW,
                              const float* __restrict__ db, float* __restrict__ dt) {
    int idx = blockIdx.x * blockDim.x + threadIdx.x;  // t*512 + d
    int d = idx & (D_INNER - 1);
    int t = idx >> 9;
    float acc = db[d];
#pragma unroll
    for (int r = 0; r < DT_RANK; r++) acc += dbl[t * 48 + r] * dW[d * DT_RANK + r];
    dt[idx] = (acc > 20.f) ? acc : log1pf(__expf(acc));
}

// ------------- sequential SSM scan, fused with D-skip and SiLU(z) gating -------------
// grid: 64 blocks = (b, d-half); thread owns one d, 16 states in registers
__global__ void scan_kernel(const float* __restrict__ xc, const float* __restrict__ dtv,
                            const float* __restrict__ dbl, const float* __restrict__ xz,
                            const float* __restrict__ A_log,
                            const float* __restrict__ Dskip,
                            float* __restrict__ yv) {
    int b = blockIdx.x >> 1;
    int d = ((blockIdx.x & 1) << 8) + threadIdx.x;  // 0..511
    float Arow[D_STATE];
#pragma unroll
    for (int s = 0; s < D_STATE; s++) Arow[s] = -expf(A_log[d * D_STATE + s]);
    float dsk = Dskip[d];
    float hst[D_STATE];
#pragma unroll
    for (int s = 0; s < D_STATE; s++) hst[s] = 0.f;
    __shared__ float Bs[D_STATE], Cs[D_STATE];
    for (int l = 0; l < SEQ; l++) {
        int t = b * SEQ + l;
        if (threadIdx.x < 32) {
            float v = dbl[t * 48 + DT_RANK + threadIdx.x];
            if (threadIdx.x < D_STATE) Bs[threadIdx.x] = v;
            else Cs[threadIdx.x - D_STATE] = v;
        }
        __syncthreads();
        float dtt = dtv[(size_t)t * D_INNER + d];
        float xv = xc[(size_t)t * D_INNER + d];
        float dtx = dtt * xv;
        float y = 0.f;
#pragma unroll
        for (int s = 0; s < D_STATE; s++) {
            float dA = __expf(dtt * Arow[s]);
            hst[s] = dA * hst[s] + dtx * Bs[s];
            y += hst[s] * Cs[s];
        }
        float z = xz[(size_t)t * (2 * D_INNER) + D_INNER + d];
        yv[(size_t)t * D_INNER + d] = (y + xv * dsk) * (z / (1.f + __expf(-z)));
        __syncthreads();
    }
}

extern "C" void kernel_launch(void* const* d_in, const int* in_sizes, int n_in,
                              void* d_out, int out_size, void* d_ws, size_t ws_size,
                              hipStream_t stream) {
    const float* coords   = (const float*)d_in[0];
    const float* emb_W    = (const float*)d_in[1];
    const float* emb_b    = (const float*)d_in[2];
    const float* ln_w     = (const float*)d_in[3];
    const float* ln_b     = (const float*)d_in[4];
    const float* in_W     = (const float*)d_in[5];
    const float* conv_W   = (const float*)d_in[6];
    const float* conv_b   = (const float*)d_in[7];
    const float* xproj_W  = (const float*)d_in[8];
    const float* dtproj_W = (const float*)d_in[9];
    const float* dtproj_b = (const float*)d_in[10];
    const float* A_log    = (const float*)d_in[11];
    const float* D_skip   = (const float*)d_in[12];
    const float* out_W    = (const float*)d_in[13];
    const float* normf_w  = (const float*)d_in[14];
    const float* normf_b  = (const float*)d_in[15];
    const float* head_W   = (const float*)d_in[16];
    float* out = (float*)d_out;

    const int T = NTOK;  // 9600
    float* x     = (float*)d_ws;
    float* resid = x + (size_t)T * D_MODEL;
    float* h     = resid + (size_t)T * D_MODEL;
    float* xz    = h + (size_t)T * D_MODEL;
    float* xc    = xz + (size_t)T * 2 * D_INNER;
    float* dbl   = xc + (size_t)T * D_INNER;
    float* dtv   = dbl + (size_t)T * 48;
    float* yv    = dtv + (size_t)T * D_INNER;

    embed_kernel<<<T, D_MODEL, 0, stream>>>(coords, emb_W, emb_b, x);

    for (int i = 0; i < N_LAYERS; i++) {
        ln_res_kernel<<<T, D_MODEL, 0, stream>>>(x, resid, h, ln_w + i * D_MODEL,
                                                 ln_b + i * D_MODEL, i == 0);
        // in_proj: (T,256) x (1024,256)^T -> (T,1024)
        gemm_tk<8><<<dim3(T / 8, 4), 256, 8 * D_MODEL * 4, stream>>>(
            h, in_W + (size_t)i * 2 * D_INNER * D_MODEL, xz, 2 * D_INNER, D_MODEL);
        conv_silu_kernel<<<T * D_INNER / 256, 256, 0, stream>>>(
            xz, conv_W + i * D_INNER * D_CONV, conv_b + i * D_INNER, xc);
        xproj_kernel<<<T, 64, 0, stream>>>(xc, xproj_W + (size_t)i * 48 * D_INNER, dbl);
        dtproj_kernel<<<T * D_INNER / 256, 256, 0, stream>>>(
            dbl, dtproj_W + (size_t)i * D_INNER * DT_RANK, dtproj_b + i * D_INNER, dtv);
        scan_kernel<<<BATCH * 2, 256, 0, stream>>>(
            xc, dtv, dbl, xz, A_log + (size_t)i * D_INNER * D_STATE, D_skip + i * D_INNER, yv);
        // out_proj: (T,512) x (256,512)^T -> (T,256)
        gemm_tk<8><<<dim3(T / 8, 1), 256, 8 * D_INNER * 4, stream>>>(
            yv, out_W + (size_t)i * D_MODEL * D_INNER, x, D_MODEL, D_INNER);
    }

    final_rms_kernel<<<T, D_MODEL, 0, stream>>>(x, resid, normf_w, normf_b, h);
    // head: (T,256) x (300,256)^T -> (T,300)
    gemm_tk<8><<<dim3(T / 8, 2), 256, 8 * D_MODEL * 4, stream>>>(
        h, head_W, out, CITY, D_MODEL);
}

// Round 3
// 1618.589 us; speedup vs baseline: 2.0291x; 2.0291x over previous
//
#include <hip/hip_runtime.h>
#include <math.h>

#define D_MODEL 256
#define D_INNER 512
#define D_STATE 16
#define D_CONV 4
#define DT_RANK 16
#define N_LAYERS 4
#define CITY 300
#define BATCH 32
#define SEQ 300
#define NTOK (BATCH * SEQ)   // 9600

// ---------------- embedding ----------------
__global__ void embed_kernel(const float* __restrict__ coords,
                             const float* __restrict__ eW,
                             const float* __restrict__ eb,
                             float* __restrict__ x) {
    int t = blockIdx.x, d = threadIdx.x;
    float c0 = coords[t * 2 + 0];
    float c1 = coords[t * 2 + 1];
    x[t * D_MODEL + d] = c0 * eW[d * 2 + 0] + c1 * eW[d * 2 + 1] + eb[d];
}

// ------------- residual add + layernorm -------------
__global__ void ln_res_kernel(const float* __restrict__ xin, float* __restrict__ resid,
                              float* __restrict__ h,
                              const float* __restrict__ w,
                              const float* __restrict__ b, int first) {
    int t = blockIdx.x, d = threadIdx.x;
    float r = xin[t * D_MODEL + d] + (first ? 0.f : resid[t * D_MODEL + d]);
    resid[t * D_MODEL + d] = r;
    __shared__ float s1[D_MODEL], s2[D_MODEL];
    s1[d] = r; s2[d] = r * r;
    __syncthreads();
    for (int off = D_MODEL / 2; off > 0; off >>= 1) {
        if (d < off) { s1[d] += s1[d + off]; s2[d] += s2[d + off]; }
        __syncthreads();
    }
    float mean = s1[0] * (1.f / D_MODEL);
    float var = s2[0] * (1.f / D_MODEL) - mean * mean;
    h[t * D_MODEL + d] = (r - mean) * rsqrtf(var + 1e-5f) * w[d] + b[d];
}

// ------------- final add + RMSNorm -------------
__global__ void final_rms_kernel(const float* __restrict__ xin, const float* __restrict__ resid,
                                 const float* __restrict__ w,
                                 const float* __restrict__ b, float* __restrict__ h) {
    int t = blockIdx.x, d = threadIdx.x;
    float r = xin[t * D_MODEL + d] + resid[t * D_MODEL + d];
    __shared__ float s2[D_MODEL];
    s2[d] = r * r;
    __syncthreads();
    for (int off = D_MODEL / 2; off > 0; off >>= 1) {
        if (d < off) s2[d] += s2[d + off];
        __syncthreads();
    }
    float rms = r * rsqrtf(s2[0] * (1.f / D_MODEL) + 1e-5f);
    h[t * D_MODEL + d] = rms * w[d] + b[d];
}

// ------------- tiled f32 GEMM: C[t,n] = sum_k A[t,k] * W[n,k] -------------
// BM x BN tile, TM x TN micro-tile, 256 threads, K-chunk 16, LDS-transposed staging.
template <int BM, int BN, int TM, int TN, bool GN>
__global__ __launch_bounds__(256, 2) void gemm_tiled(const float* __restrict__ A,
                                                     const float* __restrict__ W,
                                                     float* __restrict__ C, int N, int K) {
    __shared__ float As[16 * BM];
    __shared__ float Bs[16 * BN];
    const int t0 = blockIdx.x * BM;
    const int n0 = blockIdx.y * BN;
    const int tid = threadIdx.x;
    constexpr int MT = BM / TM;  // threads along m
    const int tx = tid % MT, ty = tid / MT;
    const int m0 = tx * TM, nn0 = ty * TN;
    float acc[TM][TN];
#pragma unroll
    for (int i = 0; i < TM; i++)
#pragma unroll
        for (int j = 0; j < TN; j++) acc[i][j] = 0.f;

    for (int k0 = 0; k0 < K; k0 += 16) {
        // stage A: BM*16 floats (BM/64 float4 per thread), transposed to As[k][m]
#pragma unroll
        for (int r = 0; r < BM / 64; r++) {
            int s = tid + 256 * r;
            int m = s >> 2, kq = s & 3;
            float4 v = *(const float4*)(A + (size_t)(t0 + m) * K + k0 + kq * 4);
            As[(kq * 4 + 0) * BM + m] = v.x;
            As[(kq * 4 + 1) * BM + m] = v.y;
            As[(kq * 4 + 2) * BM + m] = v.z;
            As[(kq * 4 + 3) * BM + m] = v.w;
        }
#pragma unroll
        for (int r = 0; r < BN / 64; r++) {
            int s = tid + 256 * r;
            int m = s >> 2, kq = s & 3;
            int nrow = n0 + m;
            float4 v = make_float4(0.f, 0.f, 0.f, 0.f);
            if (!GN || nrow < N)
                v = *(const float4*)(W + (size_t)nrow * K + k0 + kq * 4);
            Bs[(kq * 4 + 0) * BN + m] = v.x;
            Bs[(kq * 4 + 1) * BN + m] = v.y;
            Bs[(kq * 4 + 2) * BN + m] = v.z;
            Bs[(kq * 4 + 3) * BN + m] = v.w;
        }
        __syncthreads();
#pragma unroll
        for (int kc = 0; kc < 16; kc++) {
            float a[TM], b[TN];
#pragma unroll
            for (int i4 = 0; i4 < TM / 4; i4++)
                *(float4*)&a[i4 * 4] = *(const float4*)&As[kc * BM + m0 + i4 * 4];
#pragma unroll
            for (int j4 = 0; j4 < TN / 4; j4++)
                *(float4*)&b[j4 * 4] = *(const float4*)&Bs[kc * BN + nn0 + j4 * 4];
#pragma unroll
            for (int i = 0; i < TM; i++)
#pragma unroll
                for (int j = 0; j < TN; j++) acc[i][j] = fmaf(a[i], b[j], acc[i][j]);
        }
        __syncthreads();
    }
#pragma unroll
    for (int i = 0; i < TM; i++) {
        int t = t0 + m0 + i;
#pragma unroll
        for (int j4 = 0; j4 < TN / 4; j4++) {
            int n = n0 + nn0 + j4 * 4;
            if (!GN || n < N)
                *(float4*)(C + (size_t)t * N + n) =
                    make_float4(acc[i][j4 * 4], acc[i][j4 * 4 + 1],
                                acc[i][j4 * 4 + 2], acc[i][j4 * 4 + 3]);
        }
    }
}

// ------------- fused causal conv (k=4) + SiLU + xproj; wave = 2 tokens -------------
// lane owns channels [lane*8, lane*8+8); writes xc and dbl (48 outputs via butterfly)
__global__ __launch_bounds__(64) void conv_xproj_kernel(
    const float* __restrict__ xz, const float* __restrict__ cW,
    const float* __restrict__ cb, const float* __restrict__ xW,
    float* __restrict__ xc, float* __restrict__ dbl) {
    const int lane = threadIdx.x;
    const int t0 = blockIdx.x * 2;
    const int ch = lane * 8;
    // conv weights for my 8 channels (rows of 4)
    float4 cwv[8];
#pragma unroll
    for (int c = 0; c < 8; c++) cwv[c] = *(const float4*)(cW + (size_t)(ch + c) * 4);
    float4 cb0 = *(const float4*)(cb + ch);
    float4 cb1 = *(const float4*)(cb + ch + 4);
    float cbv[8] = {cb0.x, cb0.y, cb0.z, cb0.w, cb1.x, cb1.y, cb1.z, cb1.w};

    float x8[2][8];
#pragma unroll
    for (int tok = 0; tok < 2; tok++) {
        int t = t0 + tok;
        int l = t % SEQ;
        float accv[8];
#pragma unroll
        for (int c = 0; c < 8; c++) accv[c] = cbv[c];
#pragma unroll
        for (int k = 0; k < D_CONV; k++) {
            int ll = l - 3 + k;
            if (ll >= 0) {
                const float* src = xz + (size_t)(t - 3 + k) * 1024 + ch;
                float4 v0 = *(const float4*)src;
                float4 v1 = *(const float4*)(src + 4);
                float vv[8] = {v0.x, v0.y, v0.z, v0.w, v1.x, v1.y, v1.z, v1.w};
#pragma unroll
                for (int c = 0; c < 8; c++) {
                    float w = (k == 0) ? cwv[c].x : (k == 1) ? cwv[c].y
                             : (k == 2) ? cwv[c].z : cwv[c].w;
                    accv[c] = fmaf(vv[c], w, accv[c]);
                }
            }
        }
#pragma unroll
        for (int c = 0; c < 8; c++) {
            float a = accv[c];
            x8[tok][c] = a / (1.f + __expf(-a));
        }
        *(float4*)(xc + (size_t)t * 512 + ch) =
            make_float4(x8[tok][0], x8[tok][1], x8[tok][2], x8[tok][3]);
        *(float4*)(xc + (size_t)t * 512 + ch + 4) =
            make_float4(x8[tok][4], x8[tok][5], x8[tok][6], x8[tok][7]);
    }
    // xproj: 48 outputs, full-wave butterfly reduction
    float keep0 = 0.f, keep1 = 0.f;
    for (int j = 0; j < 48; j++) {
        const float* wr = xW + (size_t)j * 512 + ch;
        float4 w0 = *(const float4*)wr;
        float4 w1 = *(const float4*)(wr + 4);
        float ww[8] = {w0.x, w0.y, w0.z, w0.w, w1.x, w1.y, w1.z, w1.w};
        float a0 = 0.f, a1 = 0.f;
#pragma unroll
        for (int c = 0; c < 8; c++) {
            a0 = fmaf(ww[c], x8[0][c], a0);
            a1 = fmaf(ww[c], x8[1][c], a1);
        }
#pragma unroll
        for (int m = 1; m < 64; m <<= 1) {
            a0 += __shfl_xor(a0, m);
            a1 += __shfl_xor(a1, m);
        }
        if (lane == j) { keep0 = a0; keep1 = a1; }
    }
    if (lane < 48) {
        dbl[(size_t)t0 * 48 + lane] = keep0;
        dbl[(size_t)(t0 + 1) * 48 + lane] = keep1;
    }
}

// ------------- SSM scan with fused dtproj+softplus, D-skip, SiLU gate -------------
// 256 single-wave blocks = 32 batches x 8 d-groups; no LDS, no barriers;
// dbl row (48 floats) is wave-uniform; 1-step prefetch of next token's inputs.
__global__ __launch_bounds__(64) void scan_kernel(
    const float* __restrict__ xc, const float* __restrict__ dbl,
    const float* __restrict__ xz, const float* __restrict__ A_log,
    const float* __restrict__ Dskip, const float* __restrict__ dtW,
    const float* __restrict__ dtb, float* __restrict__ yv) {
    const int b = blockIdx.x >> 3;
    const int d = ((blockIdx.x & 7) << 6) + threadIdx.x;
    float Arow[D_STATE], dWr[DT_RANK];
#pragma unroll
    for (int s4 = 0; s4 < 4; s4++) {
        float4 v = *(const float4*)(A_log + (size_t)d * D_STATE + s4 * 4);
        Arow[s4 * 4 + 0] = -__expf(v.x);
        Arow[s4 * 4 + 1] = -__expf(v.y);
        Arow[s4 * 4 + 2] = -__expf(v.z);
        Arow[s4 * 4 + 3] = -__expf(v.w);
        float4 w = *(const float4*)(dtW + (size_t)d * DT_RANK + s4 * 4);
        dWr[s4 * 4 + 0] = w.x; dWr[s4 * 4 + 1] = w.y;
        dWr[s4 * 4 + 2] = w.z; dWr[s4 * 4 + 3] = w.w;
    }
    const float dtbv = dtb[d], dsk = Dskip[d];
    float h[D_STATE];
#pragma unroll
    for (int s = 0; s < D_STATE; s++) h[s] = 0.f;
    const size_t tb = (size_t)b * SEQ;
    const float* dr = dbl + tb * 48;
    float cur[48], nxt[48];
#pragma unroll
    for (int i = 0; i < 12; i++) ((float4*)cur)[i] = ((const float4*)dr)[i];
    float xv = xc[tb * 512 + d];
    float zv = xz[tb * 1024 + 512 + d];
    for (int l = 0; l < SEQ; l++) {
        float nxv = 0.f, nzv = 0.f;
        if (l + 1 < SEQ) {
            const float4* nr = (const float4*)(dr + (size_t)(l + 1) * 48);
#pragma unroll
            for (int i = 0; i < 12; i++) ((float4*)nxt)[i] = nr[i];
            nxv = xc[(tb + l + 1) * 512 + d];
            nzv = xz[(tb + l + 1) * 1024 + 512 + d];
        }
        // dt = softplus(dbl[0:16] . dW_row + b)
        float acc = dtbv;
#pragma unroll
        for (int r = 0; r < DT_RANK; r++) acc = fmaf(cur[r], dWr[r], acc);
        float dtt = (acc > 20.f) ? acc : log1pf(__expf(acc));
        float dtx = dtt * xv;
        float y = 0.f;
#pragma unroll
        for (int s = 0; s < D_STATE; s++) {
            float dA = __expf(dtt * Arow[s]);
            h[s] = fmaf(dA, h[s], dtx * cur[16 + s]);
            y = fmaf(h[s], cur[32 + s], y);
        }
        float sig = 1.f / (1.f + __expf(-zv));
        yv[(tb + l) * 512 + d] = (y + xv * dsk) * (zv * sig);
#pragma unroll
        for (int i = 0; i < 48; i++) cur[i] = nxt[i];
        xv = nxv; zv = nzv;
    }
}

extern "C" void kernel_launch(void* const* d_in, const int* in_sizes, int n_in,
                              void* d_out, int out_size, void* d_ws, size_t ws_size,
                              hipStream_t stream) {
    const float* coords   = (const float*)d_in[0];
    const float* emb_W    = (const float*)d_in[1];
    const float* emb_b    = (const float*)d_in[2];
    const float* ln_w     = (const float*)d_in[3];
    const float* ln_b     = (const float*)d_in[4];
    const float* in_W     = (const float*)d_in[5];
    const float* conv_W   = (const float*)d_in[6];
    const float* conv_b   = (const float*)d_in[7];
    const float* xproj_W  = (const float*)d_in[8];
    const float* dtproj_W = (const float*)d_in[9];
    const float* dtproj_b = (const float*)d_in[10];
    const float* A_log    = (const float*)d_in[11];
    const float* D_skip   = (const float*)d_in[12];
    const float* out_W    = (const float*)d_in[13];
    const float* normf_w  = (const float*)d_in[14];
    const float* normf_b  = (const float*)d_in[15];
    const float* head_W   = (const float*)d_in[16];
    float* out = (float*)d_out;

    const int T = NTOK;  // 9600
    float* x     = (float*)d_ws;
    float* resid = x + (size_t)T * D_MODEL;
    float* h     = resid + (size_t)T * D_MODEL;
    float* xz    = h + (size_t)T * D_MODEL;
    float* xc    = xz + (size_t)T * 2 * D_INNER;
    float* dbl   = xc + (size_t)T * D_INNER;
    float* yv    = dbl + (size_t)T * 48;

    embed_kernel<<<T, D_MODEL, 0, stream>>>(coords, emb_W, emb_b, x);

    for (int i = 0; i < N_LAYERS; i++) {
        ln_res_kernel<<<T, D_MODEL, 0, stream>>>(x, resid, h, ln_w + i * D_MODEL,
                                                 ln_b + i * D_MODEL, i == 0);
        // in_proj: (9600,256) x (1024,256)^T -> (9600,1024)
        gemm_tiled<128, 128, 8, 8, false><<<dim3(T / 128, 8), 256, 0, stream>>>(
            h, in_W + (size_t)i * 2 * D_INNER * D_MODEL, xz, 2 * D_INNER, D_MODEL);
        // fused conv+silu+xproj
        conv_xproj_kernel<<<T / 2, 64, 0, stream>>>(
            xz, conv_W + i * D_INNER * D_CONV, conv_b + i * D_INNER,
            xproj_W + (size_t)i * 48 * D_INNER, xc, dbl);
        // scan (dtproj fused)
        scan_kernel<<<BATCH * 8, 64, 0, stream>>>(
            xc, dbl, xz, A_log + (size_t)i * D_INNER * D_STATE, D_skip + i * D_INNER,
            dtproj_W + (size_t)i * D_INNER * DT_RANK, dtproj_b + i * D_INNER, yv);
        // out_proj: (9600,512) x (256,512)^T -> (9600,256)
        gemm_tiled<128, 64, 8, 4, false><<<dim3(T / 128, 4), 256, 0, stream>>>(
            yv, out_W + (size_t)i * D_MODEL * D_INNER, x, D_MODEL, D_INNER);
    }

    final_rms_kernel<<<T, D_MODEL, 0, stream>>>(x, resid, normf_w, normf_b, h);
    // head: (9600,256) x (300,256)^T -> (9600,300)
    gemm_tiled<128, 64, 8, 4, true><<<dim3(T / 128, 5), 256, 0, stream>>>(
        h, head_W, out, CITY, D_MODEL);
}